// Round 4
// baseline (2025.550 us; speedup 1.0000x reference)
//
#include <hip/hip_runtime.h>

typedef _Float16 half8 __attribute__((ext_vector_type(8)));
typedef float f32x4 __attribute__((ext_vector_type(4)));

#define NT 512   // timesteps
#define NB 128   // batch
#define NI 256   // input dim
#define NH 512   // hidden dim
#define NG 8     // batch groups (16 rows each)
#define NS 8     // column slices (64 cols each)

#define SIGN_MASK 0x8000800080008000ULL

// ---------------------------------------------------------------------------
// W (fp32 [N][K]) -> fragment-linear f16 for MFMA B-operand.
// Block b = t_n*KT + t_k; lane l holds 8 elems: n = t_n*16 + (l&15),
// k = t_k*32 + (l>>4)*8 + j.
// ---------------------------------------------------------------------------
__global__ void w_transform(const float* __restrict__ Whh,
                            const float* __restrict__ Win,
                            _Float16* __restrict__ Wf_hh,
                            _Float16* __restrict__ Wf_in) {
  int tid = blockIdx.x * blockDim.x + threadIdx.x;
  if (tid < 32768) {                    // W_hh: 32 n-tiles * 16 k-tiles
    int l = tid & 63, b = tid >> 6;
    int tk = b & 15, tn = b >> 4;
    int n = tn * 16 + (l & 15);
    int k = tk * 32 + (l >> 4) * 8;
    const float* src = Whh + (size_t)n * NH + k;
    _Float16* dst = Wf_hh + (size_t)tid * 8;
#pragma unroll
    for (int j = 0; j < 8; ++j) dst[j] = (_Float16)src[j];
  } else {                              // W_in: 32 n-tiles * 8 k-tiles
    int t2 = tid - 32768;
    int l = t2 & 63, b = t2 >> 6;
    int tk = b & 7, tn = b >> 3;
    int n = tn * 16 + (l & 15);
    int k = tk * 32 + (l >> 4) * 8;
    const float* src = Win + (size_t)n * NI + k;
    _Float16* dst = Wf_in + (size_t)t2 * 8;
#pragma unroll
    for (int j = 0; j < 8; ++j) dst[j] = (_Float16)src[j];
  }
}

// ---------------------------------------------------------------------------
// Phase 1: xin = x @ W_in^T (M=65536, K=256, N=512), fp32 out into d_out.
// 64-row M-tile per wg: wave wv covers n in [wv*128, +128), 4 m-tiles each,
// so each B-fragment load is reused 4x (quarter the per-CU L2 traffic of the
// 16-row version).
// ---------------------------------------------------------------------------
__global__ __launch_bounds__(256, 1)
void input_proj(const float* __restrict__ x,
                const _Float16* __restrict__ Wf_in,
                float* __restrict__ xin) {
  int lane = threadIdx.x & 63;
  int wv = threadIdx.x >> 6;
  int m0 = blockIdx.x * 64;
  int c = lane & 15, q = lane >> 4;

  f32x4 acc[4][8];
#pragma unroll
  for (int mt = 0; mt < 4; ++mt)
#pragma unroll
    for (int nt = 0; nt < 8; ++nt) acc[mt][nt] = (f32x4){0.f, 0.f, 0.f, 0.f};

#pragma unroll
  for (int kc = 0; kc < 8; ++kc) {
    half8 b[8];
#pragma unroll
    for (int nt = 0; nt < 8; ++nt)
      b[nt] = *(const half8*)(Wf_in +
               (((size_t)((wv * 8 + nt) * 8 + kc)) * 64 + lane) * 8);
#pragma unroll
    for (int mt = 0; mt < 4; ++mt) {
      int row = m0 + mt * 16 + c;
      const float4* ap =
          (const float4*)(x + (size_t)row * NI + kc * 32 + q * 8);
      float4 a0 = ap[0], a1 = ap[1];
      half8 a;
      a[0] = (_Float16)a0.x; a[1] = (_Float16)a0.y;
      a[2] = (_Float16)a0.z; a[3] = (_Float16)a0.w;
      a[4] = (_Float16)a1.x; a[5] = (_Float16)a1.y;
      a[6] = (_Float16)a1.z; a[7] = (_Float16)a1.w;
#pragma unroll
      for (int nt = 0; nt < 8; ++nt)
        acc[mt][nt] =
            __builtin_amdgcn_mfma_f32_16x16x32_f16(a, b[nt], acc[mt][nt], 0, 0, 0);
    }
  }
#pragma unroll
  for (int mt = 0; mt < 4; ++mt)
#pragma unroll
    for (int nt = 0; nt < 8; ++nt) {
      int n = wv * 128 + nt * 16 + c;
#pragma unroll
      for (int r = 0; r < 4; ++r) {
        int m = mt * 16 + q * 4 + r;
        xin[(size_t)(m0 + m) * NH + n] = acc[mt][nt][r];
      }
    }
}

// ---------------------------------------------------------------------------
// Phase 2: recurrence, 64 wgs = 8 batch-groups x 8 col-slices. Weights stay
// in VGPRs all 512 steps. Cross-slice exchange uses DATA-AS-FLAG: relu => h>=0
// => f16 sign bits free; producer tags each 8B chunk with sign-bit parity
// ((t>>1)&1), consumers poll the chunk itself until the tag matches. No flags,
// no acquire/release (single 8B atomic chunk is both data and flag).
// Double-buffered hbuf: overwrite of step-t data happens at step t+2, and P
// reaches t+2 only after polling all slices' t+1 publishes, each of which
// happens-after that slice consumed step t. xin prefetched one step ahead.
// ---------------------------------------------------------------------------
__global__ __launch_bounds__(256, 1)
void recurrence(float* __restrict__ dout,          // xin in-place -> h, + final
                const float* __restrict__ h0,
                const _Float16* __restrict__ Wf,   // fragment-linear W_hh
                _Float16* __restrict__ hbuf) {     // [2][NB][NH] f16 exchange
  __shared__ _Float16 h_sh[2][16][520];  // double-buffered A source
  __shared__ unsigned short h16s[16][72];  // epilogue->exchange bounce

  int g = blockIdx.x >> 3, s = blockIdx.x & 7;
  int tid = threadIdx.x, lane = tid & 63, wv = tid >> 6;  // 4 waves
  int c = lane & 15, q = lane >> 4;
  int m0 = g * 16;                      // batch row base
  int n0 = s * 64;                      // hidden col base
  int ncol = wv * 16 + c;               // local col this thread epilogues

  // resident B-fragments: this wave's 16-col n-tile, all K (64 VGPRs/lane)
  int nt_global = s * 4 + wv;
  half8 bfrag[16];
#pragma unroll
  for (int kc = 0; kc < 16; ++kc)
    bfrag[kc] =
        *(const half8*)(Wf + (((size_t)(nt_global * 16 + kc)) * 64 + lane) * 8);

  // fp32 master state: this thread's 4 rows x 1 col (matches C-fragment)
  float h32r[4];
#pragma unroll
  for (int r = 0; r < 4; ++r)
    h32r[r] = h0[(size_t)(m0 + q * 4 + r) * NH + n0 + ncol];

  // init h_sh[0] from h0
  for (int i = tid; i < 16 * 512; i += 256) {
    int m = i >> 9, n = i & 511;
    h_sh[0][m][n] = (_Float16)h0[(size_t)(m0 + m) * NH + n];
  }
  __syncthreads();

  unsigned long long* hb64 = (unsigned long long*)hbuf;
  int cm = tid >> 4, cc = tid & 15;     // exchange copy-out mapping

  // preload xin[0]
  float xv[4];
  {
    const float* xp = dout + (size_t)m0 * NH + n0;
#pragma unroll
    for (int r = 0; r < 4; ++r) xv[r] = xp[(size_t)(q * 4 + r) * NH + ncol];
  }

#pragma unroll 1
  for (int t = 0; t < NT; ++t) {
    int p = t & 1;

    // P = h @ Wslice^T, K=512; two acc chains
    f32x4 acc0 = (f32x4){0.f, 0.f, 0.f, 0.f};
    f32x4 acc1 = (f32x4){0.f, 0.f, 0.f, 0.f};
#pragma unroll
    for (int kc = 0; kc < 16; kc += 2) {
      half8 a0 = *(const half8*)&h_sh[p][c][kc * 32 + q * 8];
      half8 a1 = *(const half8*)&h_sh[p][c][(kc + 1) * 32 + q * 8];
      acc0 = __builtin_amdgcn_mfma_f32_16x16x32_f16(a0, bfrag[kc], acc0, 0, 0, 0);
      acc1 = __builtin_amdgcn_mfma_f32_16x16x32_f16(a1, bfrag[kc + 1], acc1, 0, 0, 0);
    }

    // prefetch next xin (at t=NT-1 this reads the final-h region: in-bounds,
    // same-thread addresses, value discarded)
    float xvn[4];
    {
      const float* xp = dout + ((size_t)(t + 1) * NB + m0) * NH + n0;
#pragma unroll
      for (int r = 0; r < 4; ++r) xvn[r] = xp[(size_t)(q * 4 + r) * NH + ncol];
    }

    // epilogue: h_new = relu(0.8 h + 0.2 (xin + P))
#pragma unroll
    for (int r = 0; r < 4; ++r) {
      int m = q * 4 + r;
      float hn = 0.8f * h32r[r] + 0.2f * (xv[r] + acc0[r] + acc1[r]);
      hn = fmaxf(hn, 0.f);
      h32r[r] = hn;
      dout[((size_t)t * NB + m0 + m) * NH + n0 + ncol] = hn;
      // mask sign (guards -0.0) — sign bit becomes the tag slot
      h16s[m][ncol] =
          (unsigned short)(__builtin_bit_cast(unsigned short, (_Float16)hn) &
                           0x7FFFu);
      if (t == NT - 1)
        dout[(size_t)NT * NB * NH + (size_t)(m0 + m) * NH + n0 + ncol] = hn;
    }
    if (t == NT - 1) break;

    __syncthreads();  // B1: h16s complete; h_sh[p] reads done

    unsigned long long pat = ((t >> 1) & 1) ? SIGN_MASK : 0ULL;

    // coalesced tagged exchange store: 256 threads x 8B
    {
      unsigned long long v = *(const unsigned long long*)&h16s[cm][cc * 4];
      __hip_atomic_store(
          hb64 + ((((size_t)p * NB + m0 + cm) * NH + n0 + cc * 4) >> 2),
          v | pat, __ATOMIC_RELAXED, __HIP_MEMORY_SCOPE_AGENT);
    }

    // poll data-as-flag + refill h_sh[p^1]
    {
      unsigned long long* hb = hb64 + ((((size_t)p * NB + m0) * NH) >> 2);
      unsigned long long v[8];
#pragma unroll
      for (int j = 0; j < 8; ++j)
        v[j] = __hip_atomic_load(hb + tid + j * 256, __ATOMIC_RELAXED,
                                 __HIP_MEMORY_SCOPE_AGENT);
#pragma unroll
      for (int j = 0; j < 8; ++j) {
        while ((v[j] & SIGN_MASK) != pat)
          v[j] = __hip_atomic_load(hb + tid + j * 256, __ATOMIC_RELAXED,
                                   __HIP_MEMORY_SCOPE_AGENT);
      }
#pragma unroll
      for (int j = 0; j < 8; ++j) {
        int k = tid + j * 256;
        int m = k >> 7, o = k & 127;
        *(unsigned long long*)&h_sh[p ^ 1][m][o * 4] = v[j] & ~SIGN_MASK;
      }
    }
    __syncthreads();  // B2: h_sh[p^1] ready for next step

#pragma unroll
    for (int r = 0; r < 4; ++r) xv[r] = xvn[r];
  }
}

// ---------------------------------------------------------------------------
extern "C" void kernel_launch(void* const* d_in, const int* in_sizes, int n_in,
                              void* d_out, int out_size, void* d_ws,
                              size_t ws_size, hipStream_t stream) {
  const float* x      = (const float*)d_in[0];   // [512][128][256]
  const float* hidden = (const float*)d_in[1];   // [128][512]
  const float* W_in   = (const float*)d_in[2];   // [512][256]
  const float* W_hh   = (const float*)d_in[3];   // [512][512]
  float* out = (float*)d_out;

  // ws: Wf_hh 512KB | Wf_in 256KB (exactly overlaid by hbuf after input_proj)
  _Float16* Wf_hh = (_Float16*)d_ws;
  _Float16* Wf_in = Wf_hh + (size_t)NH * NH;
  _Float16* hbuf  = Wf_in;   // 2*NB*NH*2 = 256KB = NH*NI*2, exact fit

  w_transform<<<192, 256, 0, stream>>>(W_hh, W_in, Wf_hh, Wf_in);
  input_proj<<<(NT * NB) / 64, 256, 0, stream>>>(x, Wf_in, out);
  // init exchange buffer: 0xFF => all sign bits 1 != first expected tag (0)
  hipMemsetAsync(hbuf, 0xFF, (size_t)2 * NB * NH * 2, stream);

  void* args[] = {(void*)&out, (void*)&hidden, (void*)&Wf_hh, (void*)&hbuf};
  hipLaunchCooperativeKernel((void*)recurrence, dim3(NG * NS), dim3(256), args,
                             0, stream);
}